// Round 9
// baseline (117.847 us; speedup 1.0000x reference)
//
#include <hip/hip_runtime.h>
#include <hip/hip_cooperative_groups.h>
#include <hip/hip_bf16.h>

namespace cg = cooperative_groups;

typedef float f32x4 __attribute__((ext_vector_type(4)));

namespace {
constexpr int kB = 4;
constexpr int kT = 4096;
constexpr int kC = 8;
constexpr int kN = kB * kT;            // 16384 tokens
constexpr int kTRows = 32;             // t-rows per block band
constexpr int kSPerThread = 4;         // s-cols per thread (f32x4 store)
constexpr int kBlockThreads = 256;
constexpr int kSTile = kBlockThreads * kSPerThread;  // 1024 s-cols per half
constexpr int kGridBlocks = 1024;      // 4 blocks/CU co-resident (coop-safe)
}

// Single cooperative kernel.
// Phase 1: each block preps 16 tokens (softmax probs p, z = -(Cmat p)) -> ws.
// grid.sync()
// Phase 2: each block = 32 t-rows x 2048 s-cols (two 1024-col tiles sharing
// the same p rows in LDS). Plain dwordx4 stores (nt proven -12us worse, R6).
__global__ __launch_bounds__(256, 4) void dam_coop(const int* __restrict__ token_ids,
                                                   const float* __restrict__ emb,
                                                   const float* __restrict__ cmat,
                                                   float* __restrict__ p_ws,
                                                   float* __restrict__ z_ws,
                                                   float* __restrict__ out) {
    const int tid = threadIdx.x;
    const int bid = blockIdx.x;

    // ---- phase 1: prep 16 tokens per block (lanes 0..15) ----
    if (tid < 16) {
        const int tok_idx = bid * 16 + tid;
        const int tok = token_ids[tok_idx];
        const f32x4* row = reinterpret_cast<const f32x4*>(emb) + (size_t)tok * 2;
        f32x4 e0 = row[0], e1 = row[1];
        float e[kC] = {e0.x, e0.y, e0.z, e0.w, e1.x, e1.y, e1.z, e1.w};
        float m = e[0];
#pragma unroll
        for (int i = 1; i < kC; ++i) m = fmaxf(m, e[i]);
        float p[kC], sum = 0.f;
#pragma unroll
        for (int i = 0; i < kC; ++i) { p[i] = __expf(e[i] - m); sum += p[i]; }
        float inv = 1.0f / sum;
#pragma unroll
        for (int i = 0; i < kC; ++i) p[i] *= inv;
        float z[kC];
#pragma unroll
        for (int c = 0; c < kC; ++c) {
            float acc = 0.f;
#pragma unroll
            for (int d = 0; d < kC; ++d) acc = fmaf(cmat[c * kC + d], p[d], acc);
            z[c] = -acc;
        }
        f32x4* po = reinterpret_cast<f32x4*>(p_ws) + (size_t)tok_idx * 2;
        po[0] = f32x4{p[0], p[1], p[2], p[3]};
        po[1] = f32x4{p[4], p[5], p[6], p[7]};
        f32x4* zo = reinterpret_cast<f32x4*>(z_ws) + (size_t)tok_idx * 2;
        zo[0] = f32x4{z[0], z[1], z[2], z[3]};
        zo[1] = f32x4{z[4], z[5], z[6], z[7]};
    }

    cg::this_grid().sync();

    // ---- phase 2: mask band ----
    // bid = (b<<8) | (ty<<1) | pairSx  -> band: 32 rows x 2048 cols
    const int pairSx = bid & 1;
    const int ty = (bid >> 1) & 127;
    const int b = bid >> 8;
    const int t0 = ty * kTRows;

    __shared__ f32x4 p_lds[kTRows * 2];   // 32 rows x 8 floats
    if (tid < kTRows * 2)
        p_lds[tid] = reinterpret_cast<const f32x4*>(p_ws + ((size_t)(b * kT + t0)) * kC)[tid];
    __syncthreads();

#pragma unroll
    for (int half = 0; half < 2; ++half) {
        const int s = (pairSx * 2 + half) * kSTile + tid * kSPerThread;
        const f32x4* zr = reinterpret_cast<const f32x4*>(z_ws) + ((size_t)(b * kT) + s) * 2;
        f32x4 zv[kSPerThread * 2];
#pragma unroll
        for (int k = 0; k < kSPerThread * 2; ++k) zv[k] = zr[k];

        float z[kSPerThread][kC];
#pragma unroll
        for (int j = 0; j < kSPerThread; ++j) {
            f32x4 a = zv[j * 2 + 0];
            f32x4 c = zv[j * 2 + 1];
            z[j][0] = a.x; z[j][1] = a.y; z[j][2] = a.z; z[j][3] = a.w;
            z[j][4] = c.x; z[j][5] = c.y; z[j][6] = c.z; z[j][7] = c.w;
        }

        float* orow = out + ((size_t)(b * kT + t0)) * kT + s;
#pragma unroll
        for (int tt = 0; tt < kTRows; ++tt) {
            f32x4 p0 = p_lds[tt * 2 + 0];
            f32x4 p1 = p_lds[tt * 2 + 1];
            float pr[kC] = {p0.x, p0.y, p0.z, p0.w, p1.x, p1.y, p1.z, p1.w};
            float r[kSPerThread];
#pragma unroll
            for (int j = 0; j < kSPerThread; ++j) {
                float acc = 0.f;   // acc = -compat
#pragma unroll
                for (int i = 0; i < kC; ++i) acc = fmaf(pr[i], z[j][i], acc);
                float ex = __expf(acc);
                r[j] = (1.f - ex) * __builtin_amdgcn_rcpf(1.f + ex);
            }
            f32x4 ov = {r[0], r[1], r[2], r[3]};
            *reinterpret_cast<f32x4*>(orow + (size_t)tt * kT) = ov;
        }
    }
}

extern "C" void kernel_launch(void* const* d_in, const int* in_sizes, int n_in,
                              void* d_out, int out_size, void* d_ws, size_t ws_size,
                              hipStream_t stream) {
    const int* token_ids = (const int*)d_in[0];
    const float* emb     = (const float*)d_in[1];
    const float* cmat    = (const float*)d_in[2];
    float* out  = (float*)d_out;
    float* p_ws = (float*)d_ws;                      // kN*8 floats
    float* z_ws = p_ws + (size_t)kN * kC;            // kN*8 floats (total 1 MB)

    void* args[] = {(void*)&token_ids, (void*)&emb, (void*)&cmat,
                    (void*)&p_ws, (void*)&z_ws, (void*)&out};
    hipLaunchCooperativeKernel((const void*)dam_coop, dim3(kGridBlocks),
                               dim3(kBlockThreads), args, 0, stream);
}

// Round 10
// 50.043 us; speedup vs baseline: 2.3549x; 2.3549x over previous
//
#include <hip/hip_runtime.h>
#include <hip/hip_bf16.h>

typedef float f32x4 __attribute__((ext_vector_type(4)));

namespace {
constexpr int kB = 4;
constexpr int kT = 4096;
constexpr int kC = 8;
constexpr int kTRows = 64;             // t-rows per block band
constexpr int kSPerThread = 4;         // s-cols per thread (f32x4 store)
constexpr int kBlockThreads = 256;
constexpr int kSTile = kBlockThreads * kSPerThread;  // 1024 s-cols
}

__device__ __forceinline__ void softmax8(const float e[kC], float p[kC]) {
    float m = e[0];
#pragma unroll
    for (int i = 1; i < kC; ++i) m = fmaxf(m, e[i]);
    float sum = 0.f;
#pragma unroll
    for (int i = 0; i < kC; ++i) { p[i] = __expf(e[i] - m); sum += p[i]; }
    float inv = __builtin_amdgcn_rcpf(sum);
#pragma unroll
    for (int i = 0; i < kC; ++i) p[i] *= inv;
}

// Fully fused, no workspace: block = 64 t-rows x 1024 s-cols.
// 64 lanes compute p rows -> LDS (1 gather each); every thread computes
// z = -(Cmat softmax(emb[tok_s])) for its 4 s-cols in registers (redundant
// across t-bands, but aggregate ~1.4us; amortized over 64 stores/thread).
// All global gathers are issued up front so HBM latency overlaps compute.
__global__ __launch_bounds__(256) void dam_fused(const int* __restrict__ token_ids,
                                                 const float* __restrict__ emb,
                                                 const float* __restrict__ cmat,
                                                 float* __restrict__ out) {
    const int b = blockIdx.z;
    const int t0 = blockIdx.y * kTRows;
    const int s0 = blockIdx.x * kSTile;
    const int tid = threadIdx.x;

    __shared__ f32x4 p_lds[kTRows * 2];   // 64 rows x 8 floats = 2 KB

    // ---- issue all gathers first ----
    f32x4 pe0, pe1;
    if (tid < kTRows) {
        int tokT = token_ids[b * kT + t0 + tid];
        const f32x4* prow = reinterpret_cast<const f32x4*>(emb) + (size_t)tokT * 2;
        pe0 = prow[0];
        pe1 = prow[1];
    }

    const int s = s0 + tid * kSPerThread;
    int4 toks = *reinterpret_cast<const int4*>(&token_ids[b * kT + s]);
    int tokS[kSPerThread] = {toks.x, toks.y, toks.z, toks.w};
    f32x4 se[kSPerThread][2];
#pragma unroll
    for (int j = 0; j < kSPerThread; ++j) {
        const f32x4* srow = reinterpret_cast<const f32x4*>(emb) + (size_t)tokS[j] * 2;
        se[j][0] = srow[0];
        se[j][1] = srow[1];
    }

    // ---- p rows -> LDS ----
    if (tid < kTRows) {
        float e[kC] = {pe0.x, pe0.y, pe0.z, pe0.w, pe1.x, pe1.y, pe1.z, pe1.w};
        float p[kC];
        softmax8(e, p);
        p_lds[tid * 2 + 0] = f32x4{p[0], p[1], p[2], p[3]};
        p_lds[tid * 2 + 1] = f32x4{p[4], p[5], p[6], p[7]};
    }
    __syncthreads();

    // ---- z for my 4 s-cols: z[c] = -sum_d cmat[c][d] * softmax(emb_s)[d] ----
    float z[kSPerThread][kC];
#pragma unroll
    for (int j = 0; j < kSPerThread; ++j) {
        float e[kC] = {se[j][0].x, se[j][0].y, se[j][0].z, se[j][0].w,
                       se[j][1].x, se[j][1].y, se[j][1].z, se[j][1].w};
        float q[kC];
        softmax8(e, q);
#pragma unroll
        for (int c = 0; c < kC; ++c) {
            float acc = 0.f;
#pragma unroll
            for (int d = 0; d < kC; ++d) acc = fmaf(cmat[c * kC + d], q[d], acc);
            z[j][c] = -acc;
        }
    }

    // ---- main loop: 64 rows x 4 cols per thread ----
    float* orow = out + ((size_t)(b * kT + t0)) * kT + s;
#pragma unroll 4
    for (int tt = 0; tt < kTRows; ++tt) {
        f32x4 p0 = p_lds[tt * 2 + 0];
        f32x4 p1 = p_lds[tt * 2 + 1];
        float pr[kC] = {p0.x, p0.y, p0.z, p0.w, p1.x, p1.y, p1.z, p1.w};
        float r[kSPerThread];
#pragma unroll
        for (int j = 0; j < kSPerThread; ++j) {
            float acc = 0.f;   // acc = -compat
#pragma unroll
            for (int i = 0; i < kC; ++i) acc = fmaf(pr[i], z[j][i], acc);
            // 2*sigmoid(-acc)-1 = (1 - e^acc) / (1 + e^acc)
            float ex = __expf(acc);
            r[j] = (1.f - ex) * __builtin_amdgcn_rcpf(1.f + ex);
        }
        f32x4 ov = {r[0], r[1], r[2], r[3]};
        *reinterpret_cast<f32x4*>(orow + (size_t)tt * kT) = ov;
    }
}

extern "C" void kernel_launch(void* const* d_in, const int* in_sizes, int n_in,
                              void* d_out, int out_size, void* d_ws, size_t ws_size,
                              hipStream_t stream) {
    const int* token_ids = (const int*)d_in[0];
    const float* emb     = (const float*)d_in[1];
    const float* cmat    = (const float*)d_in[2];
    float* out = (float*)d_out;

    dim3 grid(kT / kSTile, kT / kTRows, kB);   // (4, 64, 4) = 1024 blocks
    dam_fused<<<grid, kBlockThreads, 0, stream>>>(token_ids, emb, cmat, out);
}